// Round 1
// baseline (1309.021 us; speedup 1.0000x reference)
//
#include <hip/hip_runtime.h>
#include <hip/hip_bf16.h>

// Problem constants (fixed by the reference)
#define B_ 8
#define C_ 256
#define E_ 512
#define T_ 8192
#define K_ 512
#define CT_ (C_*T_)
#define CAP_ 32768          // candidate capacity per batch (expected ~4100)
#define SUBS_ 64            // t-subsample stride
#define SCOLS_ (T_/SUBS_)   // 128
#define SUBN_ (E_*SCOLS_)   // 65536 subsample points per batch
#define RANK_ 64            // subsample rank -> expected full count ~4096
#define NB1_ 4096           // subsample histogram bins over [-1,1)
#define NB2_ 4096           // selection histogram bins over [0,0.5)

__global__ void k_init(float* __restrict__ Z, int* __restrict__ cnt) {
    int i = threadIdx.x;
    if (i < B_) { Z[i] = 0.f; cnt[i] = 0; }
}

// rn[b,t] = 1/(||x[b,:,t]|| + 1e-8)
__global__ void k_rn(const float* __restrict__ x, float* __restrict__ rn) {
    int gid = blockIdx.x * 256 + threadIdx.x;   // B*T threads
    int b = gid / T_, t = gid % T_;
    const float* xp = x + (size_t)b * CT_ + t;
    float s0 = 0.f, s1 = 0.f, s2 = 0.f, s3 = 0.f;
    for (int c = 0; c < C_; c += 4) {
        float a0 = xp[(size_t)c * T_];
        float a1 = xp[(size_t)(c + 1) * T_];
        float a2 = xp[(size_t)(c + 2) * T_];
        float a3 = xp[(size_t)(c + 3) * T_];
        s0 += a0 * a0; s1 += a1 * a1; s2 += a2 * a2; s3 += a3 * a3;
    }
    float s = (s0 + s1) + (s2 + s3);
    rn[gid] = 1.0f / (sqrtf(s) + 1e-8f);
}

// subsampled m at t = s*64: msub[b*SUBN + e*SCOLS + s]
__global__ void k_msub(const float* __restrict__ x, const float* __restrict__ mw,
                       const float* __restrict__ mb, const float* __restrict__ rn,
                       float* __restrict__ msub) {
    int p = blockIdx.x * 256 + threadIdx.x;     // B*SUBN threads
    int s = p & (SCOLS_ - 1);
    int e = (p >> 7) & (E_ - 1);
    int b = p >> 16;
    int t = s * SUBS_;
    const float* xp = x + (size_t)b * CT_ + t;
    const float* wp = mw + (size_t)e * C_;
    float a0 = 0.f, a1 = 0.f;
    for (int c = 0; c < C_; c += 2) {
        a0 += wp[c] * xp[(size_t)c * T_];
        a1 += wp[c + 1] * xp[(size_t)(c + 1) * T_];
    }
    msub[p] = (a0 + a1) * rn[b * T_ + t] + mb[e];
}

// per-batch conservative threshold tau0 from subsample rank-64
__global__ void k_tau(const float* __restrict__ msub, float* __restrict__ tau0) {
    __shared__ int h[NB1_];
    int b = blockIdx.x, tid = threadIdx.x;
    for (int i = tid; i < NB1_; i += 256) h[i] = 0;
    __syncthreads();
    const float* mp = msub + b * SUBN_;
    for (int j = tid; j < SUBN_; j += 256) {
        float v = mp[j];
        int bin = (int)((v + 1.0f) * ((float)NB1_ * 0.5f));
        bin = bin < 0 ? 0 : (bin > NB1_ - 1 ? NB1_ - 1 : bin);
        atomicAdd(&h[bin], 1);
    }
    __syncthreads();
    if (tid == 0) {
        int cum = 0, bf = 0;
        for (int i = NB1_ - 1; i >= 0; --i) {
            cum += h[i];
            if (cum >= RANK_) { bf = i; break; }
        }
        tau0[b] = (float)bf * (2.0f / (float)NB1_) - 1.0f;  // bin lower edge
    }
}

// main GEMM: m[b,e,t] = (mask_w . x)*rn + mask_b ; accumulate Z=sum(exp(m)),
// collect candidates m >= tau0
__launch_bounds__(256)
__global__ void k_gemm(const float* __restrict__ x, const float* __restrict__ mw,
                       const float* __restrict__ mb, const float* __restrict__ rn,
                       const float* __restrict__ tau0, float* __restrict__ Z,
                       int* __restrict__ cnt, float* __restrict__ cval,
                       int* __restrict__ cidx) {
    __shared__ float As[64][68];   // As[k][i] = mask_w[e0+i][c0+k]
    __shared__ float Bs[64][68];   // Bs[k][j] = x[b][c0+k][t0+j]
    __shared__ float red[4];
    int tid = threadIdx.x;
    int tx = tid & 15, ty = tid >> 4;
    int t0 = blockIdx.x * 64, e0 = blockIdx.y * 64, b = blockIdx.z;
    const float* xb = x + (size_t)b * CT_;
    float acc[4][4] = {};
    for (int c0 = 0; c0 < C_; c0 += 64) {
#pragma unroll
        for (int r = 0; r < 4; ++r) {
            int i = (tid >> 4) + r * 16;
            int kq = (tid & 15) * 4;
            float4 av = *(const float4*)(mw + (size_t)(e0 + i) * C_ + c0 + kq);
            As[kq + 0][i] = av.x; As[kq + 1][i] = av.y;
            As[kq + 2][i] = av.z; As[kq + 3][i] = av.w;
        }
#pragma unroll
        for (int r = 0; r < 4; ++r) {
            int k = (tid >> 4) + r * 16;
            int jq = (tid & 15) * 4;
            *(float4*)(&Bs[k][jq]) =
                *(const float4*)(xb + (size_t)(c0 + k) * T_ + t0 + jq);
        }
        __syncthreads();
#pragma unroll
        for (int k = 0; k < 64; ++k) {
            float4 a = *(const float4*)(&As[k][ty * 4]);
            float4 bq = *(const float4*)(&Bs[k][tx * 4]);
            float av[4] = {a.x, a.y, a.z, a.w};
            float bv[4] = {bq.x, bq.y, bq.z, bq.w};
#pragma unroll
            for (int ii = 0; ii < 4; ++ii)
#pragma unroll
                for (int jj = 0; jj < 4; ++jj)
                    acc[ii][jj] += av[ii] * bv[jj];
        }
        __syncthreads();
    }
    float tau = tau0[b];
    float rnv[4], mbv[4];
#pragma unroll
    for (int j = 0; j < 4; ++j) rnv[j] = rn[b * T_ + t0 + tx * 4 + j];
#pragma unroll
    for (int i = 0; i < 4; ++i) mbv[i] = mb[e0 + ty * 4 + i];
    float zs = 0.f;
#pragma unroll
    for (int ii = 0; ii < 4; ++ii) {
#pragma unroll
        for (int jj = 0; jj < 4; ++jj) {
            float v = acc[ii][jj] * rnv[jj] + mbv[ii];
            zs += expf(v);
            if (v >= tau) {
                int pos = atomicAdd(&cnt[b], 1);
                if (pos < CAP_) {
                    cval[b * CAP_ + pos] = v;
                    cidx[b * CAP_ + pos] = (e0 + ty * 4 + ii) * T_ + (t0 + tx * 4 + jj);
                }
            }
        }
    }
    for (int off = 32; off; off >>= 1) zs += __shfl_down(zs, off, 64);
    if ((tid & 63) == 0) red[tid >> 6] = zs;
    __syncthreads();
    if (tid == 0) atomicAdd(&Z[b], (red[0] + red[1]) + (red[2] + red[3]));
}

// exact top-K selection among candidates (value desc, index asc on ties)
__launch_bounds__(256)
__global__ void k_select(const float* __restrict__ cval, const int* __restrict__ cidx,
                         const int* __restrict__ cnt, const float* __restrict__ Z,
                         int* __restrict__ sel_e, int* __restrict__ sel_t,
                         float* __restrict__ sel_sp) {
    __shared__ int h[NB2_];
    __shared__ float bl_v[1024];
    __shared__ int bl_i[1024];
    __shared__ int nb, bstar, nabove, outcnt;
    int b = blockIdx.x, tid = threadIdx.x;
    int n = cnt[b]; if (n > CAP_) n = CAP_;
    for (int i = tid; i < NB2_; i += 256) h[i] = 0;
    if (tid == 0) { nb = 0; outcnt = 0; }
    __syncthreads();
    const float* vp = cval + b * CAP_;
    const int* ip = cidx + b * CAP_;
    for (int j = tid; j < n; j += 256) {
        int bin = (int)(vp[j] * ((float)NB2_ * 2.0f));   // [0,0.5) range
        bin = bin < 0 ? 0 : (bin > NB2_ - 1 ? NB2_ - 1 : bin);
        atomicAdd(&h[bin], 1);
    }
    __syncthreads();
    if (tid == 0) {
        int cum = 0, bs = 0, na = 0;
        for (int i = NB2_ - 1; i >= 0; --i) {
            cum += h[i];
            if (cum >= K_) { bs = i; na = cum - h[i]; break; }
        }
        bstar = bs; nabove = na;
    }
    __syncthreads();
    int bs = bstar;
    for (int j = tid; j < n; j += 256) {
        float v = vp[j];
        int bin = (int)(v * ((float)NB2_ * 2.0f));
        bin = bin < 0 ? 0 : (bin > NB2_ - 1 ? NB2_ - 1 : bin);
        if (bin == bs) {
            int q = atomicAdd(&nb, 1);
            if (q < 1024) { bl_v[q] = v; bl_i[q] = ip[j]; }
        }
    }
    __syncthreads();
    float rZ = 1.0f / Z[b];
    for (int j = tid; j < n; j += 256) {
        float v = vp[j];
        int bin = (int)(v * ((float)NB2_ * 2.0f));
        bin = bin < 0 ? 0 : (bin > NB2_ - 1 ? NB2_ - 1 : bin);
        if (bin > bs) {
            int q = atomicAdd(&outcnt, 1);
            int idx = ip[j];
            sel_e[b * K_ + q] = idx / T_;
            sel_t[b * K_ + q] = idx % T_;
            sel_sp[b * K_ + q] = expf(v) * rZ;
        }
    }
    __syncthreads();
    if (tid == 0) {
        int m = nb; if (m > 1024) m = 1024;
        for (int i = 1; i < m; ++i) {          // insertion sort: val desc, idx asc
            float v = bl_v[i]; int id = bl_i[i]; int j = i - 1;
            while (j >= 0 && (bl_v[j] < v || (bl_v[j] == v && bl_i[j] > id))) {
                bl_v[j + 1] = bl_v[j]; bl_i[j + 1] = bl_i[j]; --j;
            }
            bl_v[j + 1] = v; bl_i[j + 1] = id;
        }
        int need = K_ - nabove;
        for (int q = 0; q < need; ++q) {
            int slot = nabove + q;
            if (q < m) {
                int idx = bl_i[q];
                sel_e[b * K_ + slot] = idx / T_;
                sel_t[b * K_ + slot] = idx % T_;
                sel_sp[b * K_ + slot] = expf(bl_v[q]) * rZ;
            } else {  // pathological fallback: harmless zero entries
                sel_e[b * K_ + slot] = 0; sel_t[b * K_ + slot] = 0;
                sel_sp[b * K_ + slot] = 0.f;
            }
        }
    }
}

// up at selected positions, g = sp * (up + up_b)
__global__ void k_upg(const float* __restrict__ x, const float* __restrict__ uw,
                      const float* __restrict__ ub, const int* __restrict__ sel_e,
                      const int* __restrict__ sel_t, const float* __restrict__ sel_sp,
                      float* __restrict__ gval) {
    int gid = blockIdx.x * 256 + threadIdx.x;   // B*K waves
    int w = gid >> 6, lane = gid & 63;
    int b = w >> 9, i = w & (K_ - 1);
    int e = sel_e[b * K_ + i], t = sel_t[b * K_ + i];
    const float* xp = x + (size_t)b * CT_ + t;
    const float* wp = uw + (size_t)e * C_;
    float acc = 0.f;
    for (int c = lane; c < C_; c += 64) acc += wp[c] * xp[(size_t)c * T_];
    for (int off = 32; off; off >>= 1) acc += __shfl_down(acc, off, 64);
    if (lane == 0) gval[b * K_ + i] = sel_sp[b * K_ + i] * (acc + ub[e]);
}

// base[b,c] = proj[b,c] + sum_b[c] + down_b[c]
__global__ void k_base(const float* __restrict__ sw, const float* __restrict__ sb,
                       const float* __restrict__ db, const int* __restrict__ sel_e,
                       const float* __restrict__ gval, float* __restrict__ base) {
    int b = blockIdx.x, c = threadIdx.x;
    float acc = 0.f;
    for (int i = 0; i < K_; ++i)
        acc += gval[b * K_ + i] * sw[(size_t)c * E_ + sel_e[b * K_ + i]];
    base[b * C_ + c] = acc + sb[c] + db[c];
}

// per (b,c): S1 = sum of spike contributions, Q = sum of squares
__global__ void k_s1q(const float* __restrict__ dw, const int* __restrict__ sel_e,
                      const float* __restrict__ gval, float* __restrict__ S1,
                      float* __restrict__ Qv) {
    int b = blockIdx.x, c = threadIdx.x;
    float s = 0.f, q = 0.f;
    for (int i = 0; i < K_; ++i) {
        float w = dw[(size_t)c * E_ + sel_e[b * K_ + i]] * gval[b * K_ + i];
        s += w; q += w * w;
    }
    S1[b * C_ + c] = s; Qv[b * C_ + c] = q;
}

// BN stats analytic: mean/var per channel, then scale + per-(b,c) output base
__global__ void k_bnstats(const float* __restrict__ base, const float* __restrict__ S1,
                          const float* __restrict__ Qv, const float* __restrict__ bnw,
                          const float* __restrict__ bnb, float* __restrict__ scalec,
                          float* __restrict__ obase) {
    int c = threadIdx.x;
    float msum = 0.f;
    for (int b = 0; b < B_; ++b) msum += (float)T_ * base[b * C_ + c] + S1[b * C_ + c];
    float mean = msum / (float)(B_ * T_);
    float vs = 0.f;
    for (int b = 0; b < B_; ++b) {
        float d = base[b * C_ + c] - mean;
        vs += (float)T_ * d * d + 2.0f * d * S1[b * C_ + c] + Qv[b * C_ + c];
    }
    float var = vs / (float)(B_ * T_);
    float sc = bnw[c] * rsqrtf(var + 1e-5f);
    scalec[c] = sc;
    for (int b = 0; b < B_; ++b)
        obase[b * C_ + c] = (base[b * C_ + c] - mean) * sc + bnb[c];
}

// fill output with column-constant base
__global__ void k_fill(const float* __restrict__ obase, float* __restrict__ out) {
    size_t gid = (size_t)blockIdx.x * 256 + threadIdx.x;
    size_t flat = gid * 4;
    int b = (int)(flat / CT_);
    int c = (int)(flat / T_) & (C_ - 1);
    float v = obase[b * C_ + c];
    float4 o = {v, v, v, v};
    *(float4*)(out + flat) = o;
}

// add spikes: out[b,c,t_i] += scale[c]*down_w[c,e_i]*g_i
__global__ void k_spikes(const float* __restrict__ dw, const float* __restrict__ scalec,
                         const int* __restrict__ sel_e, const int* __restrict__ sel_t,
                         const float* __restrict__ gval, float* __restrict__ out) {
    int gid = blockIdx.x * 256 + threadIdx.x;   // B*K*64 threads
    int s = gid >> 6, cq = (gid & 63) * 4;
    int b = s >> 9, i = s & (K_ - 1);
    int e = sel_e[b * K_ + i], t = sel_t[b * K_ + i];
    float g = gval[b * K_ + i];
#pragma unroll
    for (int q = 0; q < 4; ++q) {
        int c = cq + q;
        atomicAdd(out + (size_t)b * CT_ + (size_t)c * T_ + t,
                  scalec[c] * dw[(size_t)c * E_ + e] * g);
    }
}

extern "C" void kernel_launch(void* const* d_in, const int* in_sizes, int n_in,
                              void* d_out, int out_size, void* d_ws, size_t ws_size,
                              hipStream_t stream) {
    const float* x = (const float*)d_in[0];
    const float* up_w = (const float*)d_in[1];
    const float* up_b = (const float*)d_in[2];
    const float* mask_w = (const float*)d_in[3];
    const float* mask_b = (const float*)d_in[4];
    const float* sum_w = (const float*)d_in[5];
    const float* sum_b = (const float*)d_in[6];
    const float* down_w = (const float*)d_in[7];
    const float* down_b = (const float*)d_in[8];
    const float* bn_w = (const float*)d_in[9];
    const float* bn_b = (const float*)d_in[10];
    float* out = (float*)d_out;

    // workspace layout (floats); total ~4.6 MB
    float* ws = (float*)d_ws;
    size_t o = 0;
    float* rn = ws + o;   o += (size_t)B_ * T_;
    float* msub = ws + o; o += (size_t)B_ * SUBN_;
    float* tau0 = ws + o; o += B_;
    float* Z = ws + o;    o += B_;
    int* cnt = (int*)(ws + o);   o += B_;
    float* cval = ws + o; o += (size_t)B_ * CAP_;
    int* cidx = (int*)(ws + o);  o += (size_t)B_ * CAP_;
    int* sel_e = (int*)(ws + o); o += (size_t)B_ * K_;
    int* sel_t = (int*)(ws + o); o += (size_t)B_ * K_;
    float* sel_sp = ws + o; o += (size_t)B_ * K_;
    float* gval = ws + o;   o += (size_t)B_ * K_;
    float* base = ws + o;   o += (size_t)B_ * C_;
    float* S1 = ws + o;     o += (size_t)B_ * C_;
    float* Qv = ws + o;     o += (size_t)B_ * C_;
    float* scalec = ws + o; o += C_;
    float* obase = ws + o;  o += (size_t)B_ * C_;

    k_init<<<1, 64, 0, stream>>>(Z, cnt);
    k_rn<<<(B_ * T_) / 256, 256, 0, stream>>>(x, rn);
    k_msub<<<(B_ * SUBN_) / 256, 256, 0, stream>>>(x, mask_w, mask_b, rn, msub);
    k_tau<<<B_, 256, 0, stream>>>(msub, tau0);
    k_gemm<<<dim3(T_ / 64, E_ / 64, B_), 256, 0, stream>>>(
        x, mask_w, mask_b, rn, tau0, Z, cnt, cval, cidx);
    k_select<<<B_, 256, 0, stream>>>(cval, cidx, cnt, Z, sel_e, sel_t, sel_sp);
    k_upg<<<(B_ * K_ * 64) / 256, 256, 0, stream>>>(x, up_w, up_b, sel_e, sel_t,
                                                    sel_sp, gval);
    k_base<<<B_, C_, 0, stream>>>(sum_w, sum_b, down_b, sel_e, gval, base);
    k_s1q<<<B_, C_, 0, stream>>>(down_w, sel_e, gval, S1, Qv);
    k_bnstats<<<1, C_, 0, stream>>>(base, S1, Qv, bn_w, bn_b, scalec, obase);
    k_fill<<<(B_ * CT_ / 4) / 256, 256, 0, stream>>>(obase, out);
    k_spikes<<<(B_ * K_ * 64) / 256, 256, 0, stream>>>(down_w, scalec, sel_e, sel_t,
                                                       gval, out);
}

// Round 2
// 940.859 us; speedup vs baseline: 1.3913x; 1.3913x over previous
//
#include <hip/hip_runtime.h>
#include <hip/hip_bf16.h>

// Problem constants (fixed by the reference)
#define B_ 8
#define C_ 256
#define E_ 512
#define T_ 8192
#define K_ 512
#define CT_ (C_*T_)
#define CAP_ 32768          // candidate capacity per batch (expected ~4100)
#define SUBS_ 64            // t-subsample stride
#define SCOLS_ (T_/SUBS_)   // 128
#define SUBN_ (E_*SCOLS_)   // 65536 subsample points per batch
#define RANK_ 64            // subsample rank -> expected full count ~4096
#define NB1_ 4096           // subsample histogram bins over [-1,1)
#define NB2_ 4096           // selection histogram bins over [0,0.5)

__global__ void k_init(float* __restrict__ Z, int* __restrict__ cnt) {
    int i = threadIdx.x;
    if (i < B_) { Z[i] = 0.f; cnt[i] = 0; }
}

// rn[b,t] = 1/(||x[b,:,t]|| + 1e-8)
__global__ void k_rn(const float* __restrict__ x, float* __restrict__ rn) {
    int gid = blockIdx.x * 256 + threadIdx.x;   // B*T threads
    int b = gid / T_, t = gid % T_;
    const float* xp = x + (size_t)b * CT_ + t;
    float s0 = 0.f, s1 = 0.f, s2 = 0.f, s3 = 0.f;
    for (int c = 0; c < C_; c += 4) {
        float a0 = xp[(size_t)c * T_];
        float a1 = xp[(size_t)(c + 1) * T_];
        float a2 = xp[(size_t)(c + 2) * T_];
        float a3 = xp[(size_t)(c + 3) * T_];
        s0 += a0 * a0; s1 += a1 * a1; s2 += a2 * a2; s3 += a3 * a3;
    }
    float s = (s0 + s1) + (s2 + s3);
    rn[gid] = 1.0f / (sqrtf(s) + 1e-8f);
}

// gather subsampled, rn-scaled x: xs[b][c][s] = x[b][c][s*64] * rn[b][s*64]
__global__ void k_gather(const float* __restrict__ x, const float* __restrict__ rn,
                         float* __restrict__ xs) {
    int gid = blockIdx.x * 256 + threadIdx.x;   // B*C*SCOLS threads = 262144
    int s = gid & (SCOLS_ - 1);
    int c = (gid >> 7) & (C_ - 1);
    int b = gid >> 15;
    int t = s * SUBS_;
    xs[gid] = x[(size_t)b * CT_ + (size_t)c * T_ + t] * rn[b * T_ + t];
}

// tiled GEMM on compact gathered buffer: msub[b,e,s] = mask_w[e,:].xs[b,:,s] + mb[e]
__launch_bounds__(256)
__global__ void k_msub2(const float* __restrict__ xs, const float* __restrict__ mw,
                        const float* __restrict__ mb, float* __restrict__ msub) {
    __shared__ float As[64][68];   // As[k][i] = mask_w[e0+i][c0+k]
    __shared__ float Bs[64][68];   // Bs[k][j] = xs[b][c0+k][s0+j]
    int tid = threadIdx.x;
    int tx = tid & 15, ty = tid >> 4;
    int s0 = blockIdx.x * 64, e0 = blockIdx.y * 64, b = blockIdx.z;
    const float* xb = xs + (size_t)b * C_ * SCOLS_;
    float acc[4][4] = {};
    for (int c0 = 0; c0 < C_; c0 += 64) {
#pragma unroll
        for (int r = 0; r < 4; ++r) {
            int i = (tid >> 4) + r * 16;
            int kq = (tid & 15) * 4;
            float4 av = *(const float4*)(mw + (size_t)(e0 + i) * C_ + c0 + kq);
            As[kq + 0][i] = av.x; As[kq + 1][i] = av.y;
            As[kq + 2][i] = av.z; As[kq + 3][i] = av.w;
        }
#pragma unroll
        for (int r = 0; r < 4; ++r) {
            int k = (tid >> 4) + r * 16;
            int jq = (tid & 15) * 4;
            *(float4*)(&Bs[k][jq]) =
                *(const float4*)(xb + (size_t)(c0 + k) * SCOLS_ + s0 + jq);
        }
        __syncthreads();
#pragma unroll
        for (int k = 0; k < 64; ++k) {
            float4 a = *(const float4*)(&As[k][ty * 4]);
            float4 bq = *(const float4*)(&Bs[k][tx * 4]);
            float av[4] = {a.x, a.y, a.z, a.w};
            float bv[4] = {bq.x, bq.y, bq.z, bq.w};
#pragma unroll
            for (int ii = 0; ii < 4; ++ii)
#pragma unroll
                for (int jj = 0; jj < 4; ++jj)
                    acc[ii][jj] += av[ii] * bv[jj];
        }
        __syncthreads();
    }
#pragma unroll
    for (int ii = 0; ii < 4; ++ii) {
        float mbv = mb[e0 + ty * 4 + ii];
#pragma unroll
        for (int jj = 0; jj < 4; ++jj) {
            int e = e0 + ty * 4 + ii, s = s0 + tx * 4 + jj;
            msub[(size_t)b * SUBN_ + e * SCOLS_ + s] = acc[ii][jj] + mbv;
        }
    }
}

// per-batch conservative threshold tau0 from subsample rank-64
__global__ void k_tau(const float* __restrict__ msub, float* __restrict__ tau0) {
    __shared__ int h[NB1_];
    int b = blockIdx.x, tid = threadIdx.x;
    for (int i = tid; i < NB1_; i += 256) h[i] = 0;
    __syncthreads();
    const float* mp = msub + b * SUBN_;
    for (int j = tid; j < SUBN_; j += 256) {
        float v = mp[j];
        int bin = (int)((v + 1.0f) * ((float)NB1_ * 0.5f));
        bin = bin < 0 ? 0 : (bin > NB1_ - 1 ? NB1_ - 1 : bin);
        atomicAdd(&h[bin], 1);
    }
    __syncthreads();
    if (tid == 0) {
        int cum = 0, bf = 0;
        for (int i = NB1_ - 1; i >= 0; --i) {
            cum += h[i];
            if (cum >= RANK_) { bf = i; break; }
        }
        tau0[b] = (float)bf * (2.0f / (float)NB1_) - 1.0f;  // bin lower edge
    }
}

// main GEMM: m[b,e,t] = (mask_w . x)*rn + mask_b ; accumulate Z=sum(exp(m)),
// collect candidates m >= tau0
__launch_bounds__(256)
__global__ void k_gemm(const float* __restrict__ x, const float* __restrict__ mw,
                       const float* __restrict__ mb, const float* __restrict__ rn,
                       const float* __restrict__ tau0, float* __restrict__ Z,
                       int* __restrict__ cnt, float* __restrict__ cval,
                       int* __restrict__ cidx) {
    __shared__ float As[64][68];   // As[k][i] = mask_w[e0+i][c0+k]
    __shared__ float Bs[64][68];   // Bs[k][j] = x[b][c0+k][t0+j]
    __shared__ float red[4];
    int tid = threadIdx.x;
    int tx = tid & 15, ty = tid >> 4;
    int t0 = blockIdx.x * 64, e0 = blockIdx.y * 64, b = blockIdx.z;
    const float* xb = x + (size_t)b * CT_;
    float acc[4][4] = {};
    for (int c0 = 0; c0 < C_; c0 += 64) {
#pragma unroll
        for (int r = 0; r < 4; ++r) {
            int i = (tid >> 4) + r * 16;
            int kq = (tid & 15) * 4;
            float4 av = *(const float4*)(mw + (size_t)(e0 + i) * C_ + c0 + kq);
            As[kq + 0][i] = av.x; As[kq + 1][i] = av.y;
            As[kq + 2][i] = av.z; As[kq + 3][i] = av.w;
        }
#pragma unroll
        for (int r = 0; r < 4; ++r) {
            int k = (tid >> 4) + r * 16;
            int jq = (tid & 15) * 4;
            *(float4*)(&Bs[k][jq]) =
                *(const float4*)(xb + (size_t)(c0 + k) * T_ + t0 + jq);
        }
        __syncthreads();
#pragma unroll
        for (int k = 0; k < 64; ++k) {
            float4 a = *(const float4*)(&As[k][ty * 4]);
            float4 bq = *(const float4*)(&Bs[k][tx * 4]);
            float av[4] = {a.x, a.y, a.z, a.w};
            float bv[4] = {bq.x, bq.y, bq.z, bq.w};
#pragma unroll
            for (int ii = 0; ii < 4; ++ii)
#pragma unroll
                for (int jj = 0; jj < 4; ++jj)
                    acc[ii][jj] += av[ii] * bv[jj];
        }
        __syncthreads();
    }
    float tau = tau0[b];
    float rnv[4], mbv[4];
#pragma unroll
    for (int j = 0; j < 4; ++j) rnv[j] = rn[b * T_ + t0 + tx * 4 + j];
#pragma unroll
    for (int i = 0; i < 4; ++i) mbv[i] = mb[e0 + ty * 4 + i];
    float zs = 0.f;
#pragma unroll
    for (int ii = 0; ii < 4; ++ii) {
#pragma unroll
        for (int jj = 0; jj < 4; ++jj) {
            float v = acc[ii][jj] * rnv[jj] + mbv[ii];
            zs += expf(v);
            if (v >= tau) {
                int pos = atomicAdd(&cnt[b], 1);
                if (pos < CAP_) {
                    cval[b * CAP_ + pos] = v;
                    cidx[b * CAP_ + pos] = (e0 + ty * 4 + ii) * T_ + (t0 + tx * 4 + jj);
                }
            }
        }
    }
    for (int off = 32; off; off >>= 1) zs += __shfl_down(zs, off, 64);
    if ((tid & 63) == 0) red[tid >> 6] = zs;
    __syncthreads();
    if (tid == 0) atomicAdd(&Z[b], (red[0] + red[1]) + (red[2] + red[3]));
}

// exact top-K selection among candidates (value desc, index asc on ties)
__launch_bounds__(256)
__global__ void k_select(const float* __restrict__ cval, const int* __restrict__ cidx,
                         const int* __restrict__ cnt, const float* __restrict__ Z,
                         int* __restrict__ sel_e, int* __restrict__ sel_t,
                         float* __restrict__ sel_sp) {
    __shared__ int h[NB2_];
    __shared__ float bl_v[1024];
    __shared__ int bl_i[1024];
    __shared__ int nb, bstar, nabove, outcnt;
    int b = blockIdx.x, tid = threadIdx.x;
    int n = cnt[b]; if (n > CAP_) n = CAP_;
    for (int i = tid; i < NB2_; i += 256) h[i] = 0;
    if (tid == 0) { nb = 0; outcnt = 0; }
    __syncthreads();
    const float* vp = cval + b * CAP_;
    const int* ip = cidx + b * CAP_;
    for (int j = tid; j < n; j += 256) {
        int bin = (int)(vp[j] * ((float)NB2_ * 2.0f));   // [0,0.5) range
        bin = bin < 0 ? 0 : (bin > NB2_ - 1 ? NB2_ - 1 : bin);
        atomicAdd(&h[bin], 1);
    }
    __syncthreads();
    if (tid == 0) {
        int cum = 0, bs = 0, na = 0;
        for (int i = NB2_ - 1; i >= 0; --i) {
            cum += h[i];
            if (cum >= K_) { bs = i; na = cum - h[i]; break; }
        }
        bstar = bs; nabove = na;
    }
    __syncthreads();
    int bs = bstar;
    for (int j = tid; j < n; j += 256) {
        float v = vp[j];
        int bin = (int)(v * ((float)NB2_ * 2.0f));
        bin = bin < 0 ? 0 : (bin > NB2_ - 1 ? NB2_ - 1 : bin);
        if (bin == bs) {
            int q = atomicAdd(&nb, 1);
            if (q < 1024) { bl_v[q] = v; bl_i[q] = ip[j]; }
        }
    }
    __syncthreads();
    float rZ = 1.0f / Z[b];
    for (int j = tid; j < n; j += 256) {
        float v = vp[j];
        int bin = (int)(v * ((float)NB2_ * 2.0f));
        bin = bin < 0 ? 0 : (bin > NB2_ - 1 ? NB2_ - 1 : bin);
        if (bin > bs) {
            int q = atomicAdd(&outcnt, 1);
            int idx = ip[j];
            sel_e[b * K_ + q] = idx / T_;
            sel_t[b * K_ + q] = idx % T_;
            sel_sp[b * K_ + q] = expf(v) * rZ;
        }
    }
    __syncthreads();
    if (tid == 0) {
        int m = nb; if (m > 1024) m = 1024;
        for (int i = 1; i < m; ++i) {          // insertion sort: val desc, idx asc
            float v = bl_v[i]; int id = bl_i[i]; int j = i - 1;
            while (j >= 0 && (bl_v[j] < v || (bl_v[j] == v && bl_i[j] > id))) {
                bl_v[j + 1] = bl_v[j]; bl_i[j + 1] = bl_i[j]; --j;
            }
            bl_v[j + 1] = v; bl_i[j + 1] = id;
        }
        int need = K_ - nabove;
        for (int q = 0; q < need; ++q) {
            int slot = nabove + q;
            if (q < m) {
                int idx = bl_i[q];
                sel_e[b * K_ + slot] = idx / T_;
                sel_t[b * K_ + slot] = idx % T_;
                sel_sp[b * K_ + slot] = expf(bl_v[q]) * rZ;
            } else {  // pathological fallback: harmless zero entries
                sel_e[b * K_ + slot] = 0; sel_t[b * K_ + slot] = 0;
                sel_sp[b * K_ + slot] = 0.f;
            }
        }
    }
}

// up at selected positions, g = sp * (up + up_b)
__global__ void k_upg(const float* __restrict__ x, const float* __restrict__ uw,
                      const float* __restrict__ ub, const int* __restrict__ sel_e,
                      const int* __restrict__ sel_t, const float* __restrict__ sel_sp,
                      float* __restrict__ gval) {
    int gid = blockIdx.x * 256 + threadIdx.x;   // B*K waves
    int w = gid >> 6, lane = gid & 63;
    int b = w >> 9, i = w & (K_ - 1);
    int e = sel_e[b * K_ + i], t = sel_t[b * K_ + i];
    const float* xp = x + (size_t)b * CT_ + t;
    const float* wp = uw + (size_t)e * C_;
    float acc = 0.f;
    for (int c = lane; c < C_; c += 64) acc += wp[c] * xp[(size_t)c * T_];
    for (int off = 32; off; off >>= 1) acc += __shfl_down(acc, off, 64);
    if (lane == 0) gval[b * K_ + i] = sel_sp[b * K_ + i] * (acc + ub[e]);
}

// base[b,c] = proj[b,c] + sum_b[c] + down_b[c]
__global__ void k_base(const float* __restrict__ sw, const float* __restrict__ sb,
                       const float* __restrict__ db, const int* __restrict__ sel_e,
                       const float* __restrict__ gval, float* __restrict__ base) {
    int b = blockIdx.x, c = threadIdx.x;
    float acc = 0.f;
    for (int i = 0; i < K_; ++i)
        acc += gval[b * K_ + i] * sw[(size_t)c * E_ + sel_e[b * K_ + i]];
    base[b * C_ + c] = acc + sb[c] + db[c];
}

// per (b,c): S1 = sum of spike contributions, Q = sum of squares
__global__ void k_s1q(const float* __restrict__ dw, const int* __restrict__ sel_e,
                      const float* __restrict__ gval, float* __restrict__ S1,
                      float* __restrict__ Qv) {
    int b = blockIdx.x, c = threadIdx.x;
    float s = 0.f, q = 0.f;
    for (int i = 0; i < K_; ++i) {
        float w = dw[(size_t)c * E_ + sel_e[b * K_ + i]] * gval[b * K_ + i];
        s += w; q += w * w;
    }
    S1[b * C_ + c] = s; Qv[b * C_ + c] = q;
}

// BN stats analytic: mean/var per channel, then scale + per-(b,c) output base
__global__ void k_bnstats(const float* __restrict__ base, const float* __restrict__ S1,
                          const float* __restrict__ Qv, const float* __restrict__ bnw,
                          const float* __restrict__ bnb, float* __restrict__ scalec,
                          float* __restrict__ obase) {
    int c = threadIdx.x;
    float msum = 0.f;
    for (int b = 0; b < B_; ++b) msum += (float)T_ * base[b * C_ + c] + S1[b * C_ + c];
    float mean = msum / (float)(B_ * T_);
    float vs = 0.f;
    for (int b = 0; b < B_; ++b) {
        float d = base[b * C_ + c] - mean;
        vs += (float)T_ * d * d + 2.0f * d * S1[b * C_ + c] + Qv[b * C_ + c];
    }
    float var = vs / (float)(B_ * T_);
    float sc = bnw[c] * rsqrtf(var + 1e-5f);
    scalec[c] = sc;
    for (int b = 0; b < B_; ++b)
        obase[b * C_ + c] = (base[b * C_ + c] - mean) * sc + bnb[c];
}

// fill output with column-constant base
__global__ void k_fill(const float* __restrict__ obase, float* __restrict__ out) {
    size_t gid = (size_t)blockIdx.x * 256 + threadIdx.x;
    size_t flat = gid * 4;
    int b = (int)(flat / CT_);
    int c = (int)(flat / T_) & (C_ - 1);
    float v = obase[b * C_ + c];
    float4 o = {v, v, v, v};
    *(float4*)(out + flat) = o;
}

// add spikes: out[b,c,t_i] += scale[c]*down_w[c,e_i]*g_i
__global__ void k_spikes(const float* __restrict__ dw, const float* __restrict__ scalec,
                         const int* __restrict__ sel_e, const int* __restrict__ sel_t,
                         const float* __restrict__ gval, float* __restrict__ out) {
    int gid = blockIdx.x * 256 + threadIdx.x;   // B*K*64 threads
    int s = gid >> 6, cq = (gid & 63) * 4;
    int b = s >> 9, i = s & (K_ - 1);
    int e = sel_e[b * K_ + i], t = sel_t[b * K_ + i];
    float g = gval[b * K_ + i];
#pragma unroll
    for (int q = 0; q < 4; ++q) {
        int c = cq + q;
        atomicAdd(out + (size_t)b * CT_ + (size_t)c * T_ + t,
                  scalec[c] * dw[(size_t)c * E_ + e] * g);
    }
}

extern "C" void kernel_launch(void* const* d_in, const int* in_sizes, int n_in,
                              void* d_out, int out_size, void* d_ws, size_t ws_size,
                              hipStream_t stream) {
    const float* x = (const float*)d_in[0];
    const float* up_w = (const float*)d_in[1];
    const float* up_b = (const float*)d_in[2];
    const float* mask_w = (const float*)d_in[3];
    const float* mask_b = (const float*)d_in[4];
    const float* sum_w = (const float*)d_in[5];
    const float* sum_b = (const float*)d_in[6];
    const float* down_w = (const float*)d_in[7];
    const float* down_b = (const float*)d_in[8];
    const float* bn_w = (const float*)d_in[9];
    const float* bn_b = (const float*)d_in[10];
    float* out = (float*)d_out;

    // workspace layout (floats); total ~5.6 MB
    float* ws = (float*)d_ws;
    size_t o = 0;
    float* rn = ws + o;   o += (size_t)B_ * T_;
    float* xs = ws + o;   o += (size_t)B_ * C_ * SCOLS_;
    float* msub = ws + o; o += (size_t)B_ * SUBN_;
    float* tau0 = ws + o; o += B_;
    float* Z = ws + o;    o += B_;
    int* cnt = (int*)(ws + o);   o += B_;
    float* cval = ws + o; o += (size_t)B_ * CAP_;
    int* cidx = (int*)(ws + o);  o += (size_t)B_ * CAP_;
    int* sel_e = (int*)(ws + o); o += (size_t)B_ * K_;
    int* sel_t = (int*)(ws + o); o += (size_t)B_ * K_;
    float* sel_sp = ws + o; o += (size_t)B_ * K_;
    float* gval = ws + o;   o += (size_t)B_ * K_;
    float* base = ws + o;   o += (size_t)B_ * C_;
    float* S1 = ws + o;     o += (size_t)B_ * C_;
    float* Qv = ws + o;     o += (size_t)B_ * C_;
    float* scalec = ws + o; o += C_;
    float* obase = ws + o;  o += (size_t)B_ * C_;

    k_init<<<1, 64, 0, stream>>>(Z, cnt);
    k_rn<<<(B_ * T_) / 256, 256, 0, stream>>>(x, rn);
    k_gather<<<(B_ * C_ * SCOLS_) / 256, 256, 0, stream>>>(x, rn, xs);
    k_msub2<<<dim3(SCOLS_ / 64, E_ / 64, B_), 256, 0, stream>>>(xs, mask_w, mask_b, msub);
    k_tau<<<B_, 256, 0, stream>>>(msub, tau0);
    k_gemm<<<dim3(T_ / 64, E_ / 64, B_), 256, 0, stream>>>(
        x, mask_w, mask_b, rn, tau0, Z, cnt, cval, cidx);
    k_select<<<B_, 256, 0, stream>>>(cval, cidx, cnt, Z, sel_e, sel_t, sel_sp);
    k_upg<<<(B_ * K_ * 64) / 256, 256, 0, stream>>>(x, up_w, up_b, sel_e, sel_t,
                                                    sel_sp, gval);
    k_base<<<B_, C_, 0, stream>>>(sum_w, sum_b, down_b, sel_e, gval, base);
    k_s1q<<<B_, C_, 0, stream>>>(down_w, sel_e, gval, S1, Qv);
    k_bnstats<<<1, C_, 0, stream>>>(base, S1, Qv, bn_w, bn_b, scalec, obase);
    k_fill<<<(B_ * CT_ / 4) / 256, 256, 0, stream>>>(obase, out);
    k_spikes<<<(B_ * K_ * 64) / 256, 256, 0, stream>>>(down_w, scalec, sel_e, sel_t,
                                                       gval, out);
}

// Round 3
// 631.671 us; speedup vs baseline: 2.0723x; 1.4895x over previous
//
#include <hip/hip_runtime.h>
#include <hip/hip_bf16.h>

// Problem constants (fixed by the reference)
#define B_ 8
#define C_ 256
#define E_ 512
#define T_ 8192
#define K_ 512
#define CT_ (C_*T_)
#define CAP_ 32768          // candidate capacity per batch (expected ~4100)
#define SUBS_ 64            // t-subsample stride
#define SCOLS_ (T_/SUBS_)   // 128
#define SUBN_ (E_*SCOLS_)   // 65536 subsample points per batch
#define RANK_ 64            // subsample rank -> expected full count ~4096
#define NB1_ 4096           // subsample histogram bins over [-1,1)
#define NB2_ 4096           // selection histogram bins over [0,0.5)

typedef __attribute__((ext_vector_type(8))) short bf16x8;
typedef __attribute__((ext_vector_type(4))) float f32x4;

__device__ inline ushort f2bf(float f) {
    __hip_bfloat16 h = __float2bfloat16(f);
    return *reinterpret_cast<ushort*>(&h);
}
__device__ inline float bf2f(ushort u) {
    __hip_bfloat16 h = *reinterpret_cast<__hip_bfloat16*>(&u);
    return __bfloat162float(h);
}

// rn[b,t] = 1/(||x[b,:,t]|| + 1e-8); block 0 also inits Z, cnt
__global__ void k_rn(const float* __restrict__ x, float* __restrict__ rn,
                     float* __restrict__ Z, int* __restrict__ cnt) {
    if (blockIdx.x == 0 && threadIdx.x < B_) {
        Z[threadIdx.x] = 0.f; cnt[threadIdx.x] = 0;
    }
    int gid = blockIdx.x * 256 + threadIdx.x;   // B*T threads
    int b = gid / T_, t = gid % T_;
    const float* xp = x + (size_t)b * CT_ + t;
    float s0 = 0.f, s1 = 0.f, s2 = 0.f, s3 = 0.f;
    for (int c = 0; c < C_; c += 4) {
        float a0 = xp[(size_t)c * T_];
        float a1 = xp[(size_t)(c + 1) * T_];
        float a2 = xp[(size_t)(c + 2) * T_];
        float a3 = xp[(size_t)(c + 3) * T_];
        s0 += a0 * a0; s1 += a1 * a1; s2 += a2 * a2; s3 += a3 * a3;
    }
    float s = (s0 + s1) + (s2 + s3);
    rn[gid] = 1.0f / (sqrtf(s) + 1e-8f);
}

// gather subsampled, rn-scaled x: xs[b][c][s] = x[b][c][s*64] * rn[b][s*64]
__global__ void k_gather(const float* __restrict__ x, const float* __restrict__ rn,
                         float* __restrict__ xs) {
    int gid = blockIdx.x * 256 + threadIdx.x;   // B*C*SCOLS threads = 262144
    int s = gid & (SCOLS_ - 1);
    int c = (gid >> 7) & (C_ - 1);
    int b = gid >> 15;
    int t = s * SUBS_;
    xs[gid] = x[(size_t)b * CT_ + (size_t)c * T_ + t] * rn[b * T_ + t];
}

// tiled f32 GEMM on compact gathered buffer (small: ~270 MFLOP)
__launch_bounds__(256)
__global__ void k_msub2(const float* __restrict__ xs, const float* __restrict__ mw,
                        const float* __restrict__ mb, float* __restrict__ msub) {
    __shared__ float As[64][68];
    __shared__ float Bs[64][68];
    int tid = threadIdx.x;
    int tx = tid & 15, ty = tid >> 4;
    int s0 = blockIdx.x * 64, e0 = blockIdx.y * 64, b = blockIdx.z;
    const float* xb = xs + (size_t)b * C_ * SCOLS_;
    float acc[4][4] = {};
    for (int c0 = 0; c0 < C_; c0 += 64) {
#pragma unroll
        for (int r = 0; r < 4; ++r) {
            int i = (tid >> 4) + r * 16;
            int kq = (tid & 15) * 4;
            float4 av = *(const float4*)(mw + (size_t)(e0 + i) * C_ + c0 + kq);
            As[kq + 0][i] = av.x; As[kq + 1][i] = av.y;
            As[kq + 2][i] = av.z; As[kq + 3][i] = av.w;
        }
#pragma unroll
        for (int r = 0; r < 4; ++r) {
            int k = (tid >> 4) + r * 16;
            int jq = (tid & 15) * 4;
            *(float4*)(&Bs[k][jq]) =
                *(const float4*)(xb + (size_t)(c0 + k) * SCOLS_ + s0 + jq);
        }
        __syncthreads();
#pragma unroll
        for (int k = 0; k < 64; ++k) {
            float4 a = *(const float4*)(&As[k][ty * 4]);
            float4 bq = *(const float4*)(&Bs[k][tx * 4]);
            float av[4] = {a.x, a.y, a.z, a.w};
            float bv[4] = {bq.x, bq.y, bq.z, bq.w};
#pragma unroll
            for (int ii = 0; ii < 4; ++ii)
#pragma unroll
                for (int jj = 0; jj < 4; ++jj)
                    acc[ii][jj] += av[ii] * bv[jj];
        }
        __syncthreads();
    }
#pragma unroll
    for (int ii = 0; ii < 4; ++ii) {
        float mbv = mb[e0 + ty * 4 + ii];
#pragma unroll
        for (int jj = 0; jj < 4; ++jj) {
            int e = e0 + ty * 4 + ii, s = s0 + tx * 4 + jj;
            msub[(size_t)b * SUBN_ + e * SCOLS_ + s] = acc[ii][jj] + mbv;
        }
    }
}

// per-batch conservative threshold tau0 from subsample rank-64
__global__ void k_tau(const float* __restrict__ msub, float* __restrict__ tau0) {
    __shared__ int h[NB1_];
    __shared__ int part[256];
    int b = blockIdx.x, tid = threadIdx.x;
    for (int i = tid; i < NB1_; i += 256) h[i] = 0;
    __syncthreads();
    const float* mp = msub + b * SUBN_;
    for (int j = tid; j < SUBN_; j += 256) {
        float v = mp[j];
        int bin = (int)((v + 1.0f) * ((float)NB1_ * 0.5f));
        bin = bin < 0 ? 0 : (bin > NB1_ - 1 ? NB1_ - 1 : bin);
        atomicAdd(&h[bin], 1);
    }
    __syncthreads();
    int ps = 0;
    for (int j = 0; j < 16; ++j) ps += h[tid * 16 + j];
    part[tid] = ps;
    __syncthreads();
    if (tid == 0) {
        int cum = 0, bf = 0;
        for (int i = 255; i >= 0; --i) {
            if (cum + part[i] >= RANK_) {
                int cum2 = cum;
                for (int j = 15; j >= 0; --j) {
                    cum2 += h[i * 16 + j];
                    if (cum2 >= RANK_) { bf = i * 16 + j; break; }
                }
                break;
            }
            cum += part[i];
        }
        tau0[b] = (float)bf * (2.0f / (float)NB1_) - 1.0f;  // bin lower edge
    }
}

// ---------------- main GEMM: split-bf16 MFMA ----------------
// m[b,e,t] = (mask_w . x)*rn + mask_b ; Z += sum(exp(m)); collect m >= tau0.
// a*b ~= ahi*bhi + ahi*blo + alo*bhi  (3x mfma_f32_16x16x32_bf16)
#define PADC 88   // ushort row stride: 176B = 16B-aligned, 2-way banks (free)
__launch_bounds__(256)
__global__ void k_gemm(const float* __restrict__ x, const float* __restrict__ mw,
                       const float* __restrict__ mb, const float* __restrict__ rn,
                       const float* __restrict__ tau0, float* __restrict__ Z,
                       int* __restrict__ cnt, float* __restrict__ cval,
                       int* __restrict__ cidx) {
    __shared__ ushort Ah[64][PADC], Al[64][PADC];   // [e][c]
    __shared__ ushort Bh[64][PADC], Bl[64][PADC];   // [t][c] (transposed x)
    __shared__ float red[4];
    int tid = threadIdx.x;
    int lane = tid & 63, w = tid >> 6;
    int t0 = blockIdx.x * 64, e0 = blockIdx.y * 64, b = blockIdx.z;
    const float* xb = x + (size_t)b * CT_;
    f32x4 acc[4] = {{0.f,0.f,0.f,0.f},{0.f,0.f,0.f,0.f},
                    {0.f,0.f,0.f,0.f},{0.f,0.f,0.f,0.f}};
    int arow = w * 16 + (lane & 15);       // LDS row for A frags (e within tile)
    int koff = (lane >> 4) * 8;            // k offset within 32-wide MFMA step

    for (int cc0 = 0; cc0 < C_; cc0 += 64) {
        // stage A: mask_w[e0..e0+63][cc0..cc0+63] -> Ah/Al[e][c]
#pragma unroll
        for (int q = 0; q < 4; ++q) {
            int idx = tid + q * 256;
            int er = idx >> 4, c4 = (idx & 15) * 4;
            float4 v = *(const float4*)(mw + (size_t)(e0 + er) * C_ + cc0 + c4);
            ushort4 h, l;
            h.x = f2bf(v.x); l.x = f2bf(v.x - bf2f(h.x));
            h.y = f2bf(v.y); l.y = f2bf(v.y - bf2f(h.y));
            h.z = f2bf(v.z); l.z = f2bf(v.z - bf2f(h.z));
            h.w = f2bf(v.w); l.w = f2bf(v.w - bf2f(h.w));
            *(ushort4*)&Ah[er][c4] = h;
            *(ushort4*)&Al[er][c4] = l;
        }
        // stage B (transpose): x[cc0+cr][t0..t0+63] -> Bh/Bl[t][cr]
#pragma unroll
        for (int q = 0; q < 4; ++q) {
            int idx = tid + q * 256;
            int cr = idx >> 4, t4 = (idx & 15) * 4;
            float4 v = *(const float4*)(xb + (size_t)(cc0 + cr) * T_ + t0 + t4);
            float vv[4] = {v.x, v.y, v.z, v.w};
#pragma unroll
            for (int j = 0; j < 4; ++j) {
                ushort h = f2bf(vv[j]);
                Bh[t4 + j][cr] = h;
                Bl[t4 + j][cr] = f2bf(vv[j] - bf2f(h));
            }
        }
        __syncthreads();
#pragma unroll
        for (int ks = 0; ks < 2; ++ks) {
            int cb = ks * 32 + koff;
            bf16x8 ah = *(const bf16x8*)&Ah[arow][cb];
            bf16x8 al = *(const bf16x8*)&Al[arow][cb];
#pragma unroll
            for (int n = 0; n < 4; ++n) {
                int brow = n * 16 + (lane & 15);
                bf16x8 bh = *(const bf16x8*)&Bh[brow][cb];
                bf16x8 bl = *(const bf16x8*)&Bl[brow][cb];
                acc[n] = __builtin_amdgcn_mfma_f32_16x16x32_bf16(ah, bh, acc[n], 0, 0, 0);
                acc[n] = __builtin_amdgcn_mfma_f32_16x16x32_bf16(ah, bl, acc[n], 0, 0, 0);
                acc[n] = __builtin_amdgcn_mfma_f32_16x16x32_bf16(al, bh, acc[n], 0, 0, 0);
            }
        }
        __syncthreads();
    }
    // epilogue: C/D layout col=lane&15, row=(lane>>4)*4+reg
    float tau = tau0[b];
    float zs = 0.f;
#pragma unroll
    for (int n = 0; n < 4; ++n) {
        int t = t0 + n * 16 + (lane & 15);
        float rnv = rn[b * T_ + t];
#pragma unroll
        for (int r = 0; r < 4; ++r) {
            int e = e0 + w * 16 + (lane >> 4) * 4 + r;
            float v = acc[n][r] * rnv + mb[e];
            zs += expf(v);
            if (v >= tau) {
                int pos = atomicAdd(&cnt[b], 1);
                if (pos < CAP_) {
                    cval[b * CAP_ + pos] = v;
                    cidx[b * CAP_ + pos] = e * T_ + t;
                }
            }
        }
    }
#pragma unroll
    for (int off = 32; off; off >>= 1) zs += __shfl_xor(zs, off, 64);
    if (lane == 0) red[w] = zs;
    __syncthreads();
    if (tid == 0) atomicAdd(&Z[b], (red[0] + red[1]) + (red[2] + red[3]));
}

// exact top-K selection among candidates (value desc, index asc on ties)
__launch_bounds__(256)
__global__ void k_select(const float* __restrict__ cval, const int* __restrict__ cidx,
                         const int* __restrict__ cnt, const float* __restrict__ Z,
                         int* __restrict__ sel_e, int* __restrict__ sel_t,
                         float* __restrict__ sel_sp) {
    __shared__ int h[NB2_];
    __shared__ int part[256];
    __shared__ float bl_v[1024];
    __shared__ int bl_i[1024];
    __shared__ int nb, bstar, nabove, outcnt;
    int b = blockIdx.x, tid = threadIdx.x;
    int n = cnt[b]; if (n > CAP_) n = CAP_;
    for (int i = tid; i < NB2_; i += 256) h[i] = 0;
    if (tid == 0) { nb = 0; outcnt = 0; }
    __syncthreads();
    const float* vp = cval + b * CAP_;
    const int* ip = cidx + b * CAP_;
    for (int j = tid; j < n; j += 256) {
        int bin = (int)(vp[j] * ((float)NB2_ * 2.0f));   // [0,0.5) range
        bin = bin < 0 ? 0 : (bin > NB2_ - 1 ? NB2_ - 1 : bin);
        atomicAdd(&h[bin], 1);
    }
    __syncthreads();
    int ps = 0;
    for (int j = 0; j < 16; ++j) ps += h[tid * 16 + j];
    part[tid] = ps;
    __syncthreads();
    if (tid == 0) {
        int cum = 0, bs = 0, na = 0;
        for (int i = 255; i >= 0; --i) {
            if (cum + part[i] >= K_) {
                int cum2 = cum;
                for (int j = 15; j >= 0; --j) {
                    cum2 += h[i * 16 + j];
                    if (cum2 >= K_) { bs = i * 16 + j; na = cum2 - h[i * 16 + j]; break; }
                }
                break;
            }
            cum += part[i];
        }
        bstar = bs; nabove = na;
    }
    __syncthreads();
    int bs = bstar;
    for (int j = tid; j < n; j += 256) {
        float v = vp[j];
        int bin = (int)(v * ((float)NB2_ * 2.0f));
        bin = bin < 0 ? 0 : (bin > NB2_ - 1 ? NB2_ - 1 : bin);
        if (bin == bs) {
            int q = atomicAdd(&nb, 1);
            if (q < 1024) { bl_v[q] = v; bl_i[q] = ip[j]; }
        }
    }
    __syncthreads();
    float rZ = 1.0f / Z[b];
    for (int j = tid; j < n; j += 256) {
        float v = vp[j];
        int bin = (int)(v * ((float)NB2_ * 2.0f));
        bin = bin < 0 ? 0 : (bin > NB2_ - 1 ? NB2_ - 1 : bin);
        if (bin > bs) {
            int q = atomicAdd(&outcnt, 1);
            int idx = ip[j];
            sel_e[b * K_ + q] = idx / T_;
            sel_t[b * K_ + q] = idx % T_;
            sel_sp[b * K_ + q] = expf(v) * rZ;
        }
    }
    __syncthreads();
    if (tid == 0) {
        int m = nb; if (m > 1024) m = 1024;
        for (int i = 1; i < m; ++i) {          // insertion sort: val desc, idx asc
            float v = bl_v[i]; int id = bl_i[i]; int j = i - 1;
            while (j >= 0 && (bl_v[j] < v || (bl_v[j] == v && bl_i[j] > id))) {
                bl_v[j + 1] = bl_v[j]; bl_i[j + 1] = bl_i[j]; --j;
            }
            bl_v[j + 1] = v; bl_i[j + 1] = id;
        }
        int need = K_ - nabove;
        for (int q = 0; q < need; ++q) {
            int slot = nabove + q;
            if (q < m) {
                int idx = bl_i[q];
                sel_e[b * K_ + slot] = idx / T_;
                sel_t[b * K_ + slot] = idx % T_;
                sel_sp[b * K_ + slot] = expf(bl_v[q]) * rZ;
            } else {  // pathological fallback: harmless zero entries
                sel_e[b * K_ + slot] = 0; sel_t[b * K_ + slot] = 0;
                sel_sp[b * K_ + slot] = 0.f;
            }
        }
    }
}

// up at selected positions, g = sp * (up + up_b)  (f32 for precision)
__global__ void k_upg(const float* __restrict__ x, const float* __restrict__ uw,
                      const float* __restrict__ ub, const int* __restrict__ sel_e,
                      const int* __restrict__ sel_t, const float* __restrict__ sel_sp,
                      float* __restrict__ gval) {
    int gid = blockIdx.x * 256 + threadIdx.x;   // B*K waves
    int w = gid >> 6, lane = gid & 63;
    int b = w >> 9, i = w & (K_ - 1);
    int e = sel_e[b * K_ + i], t = sel_t[b * K_ + i];
    const float* xp = x + (size_t)b * CT_ + t;
    const float* wp = uw + (size_t)e * C_;
    float acc = 0.f;
    for (int c = lane; c < C_; c += 64) acc += wp[c] * xp[(size_t)c * T_];
    for (int off = 32; off; off >>= 1) acc += __shfl_down(acc, off, 64);
    if (lane == 0) gval[b * K_ + i] = sel_sp[b * K_ + i] * (acc + ub[e]);
}

// merged base + S1/Q: one wave per (b,c)
__global__ void k_bsq(const float* __restrict__ sw, const float* __restrict__ sb,
                      const float* __restrict__ db, const float* __restrict__ dw,
                      const int* __restrict__ sel_e, const float* __restrict__ gval,
                      float* __restrict__ base, float* __restrict__ S1,
                      float* __restrict__ Qv) {
    int wg = blockIdx.x * 4 + (threadIdx.x >> 6);   // 2048 waves
    int lane = threadIdx.x & 63;
    int b = wg >> 8, c = wg & (C_ - 1);
    float p = 0.f, s = 0.f, q = 0.f;
    for (int i = lane; i < K_; i += 64) {
        int e = sel_e[b * K_ + i];
        float g = gval[b * K_ + i];
        p += g * sw[(size_t)c * E_ + e];
        float wv = dw[(size_t)c * E_ + e] * g;
        s += wv; q += wv * wv;
    }
#pragma unroll
    for (int off = 32; off; off >>= 1) {
        p += __shfl_xor(p, off, 64);
        s += __shfl_xor(s, off, 64);
        q += __shfl_xor(q, off, 64);
    }
    if (lane == 0) {
        base[b * C_ + c] = p + sb[c] + db[c];
        S1[b * C_ + c] = s; Qv[b * C_ + c] = q;
    }
}

// BN stats analytic: mean/var per channel, then scale + per-(b,c) output base
__global__ void k_bnstats(const float* __restrict__ base, const float* __restrict__ S1,
                          const float* __restrict__ Qv, const float* __restrict__ bnw,
                          const float* __restrict__ bnb, float* __restrict__ scalec,
                          float* __restrict__ obase) {
    int c = threadIdx.x;
    float msum = 0.f;
    for (int b = 0; b < B_; ++b) msum += (float)T_ * base[b * C_ + c] + S1[b * C_ + c];
    float mean = msum / (float)(B_ * T_);
    float vs = 0.f;
    for (int b = 0; b < B_; ++b) {
        float d = base[b * C_ + c] - mean;
        vs += (float)T_ * d * d + 2.0f * d * S1[b * C_ + c] + Qv[b * C_ + c];
    }
    float var = vs / (float)(B_ * T_);
    float sc = bnw[c] * rsqrtf(var + 1e-5f);
    scalec[c] = sc;
    for (int b = 0; b < B_; ++b)
        obase[b * C_ + c] = (base[b * C_ + c] - mean) * sc + bnb[c];
}

// fill output with column-constant base
__global__ void k_fill(const float* __restrict__ obase, float* __restrict__ out) {
    size_t gid = (size_t)blockIdx.x * 256 + threadIdx.x;
    size_t flat = gid * 4;
    int b = (int)(flat / CT_);
    int c = (int)(flat / T_) & (C_ - 1);
    float v = obase[b * C_ + c];
    float4 o = {v, v, v, v};
    *(float4*)(out + flat) = o;
}

// add spikes: out[b,c,t_i] += scale[c]*down_w[c,e_i]*g_i
__global__ void k_spikes(const float* __restrict__ dw, const float* __restrict__ scalec,
                         const int* __restrict__ sel_e, const int* __restrict__ sel_t,
                         const float* __restrict__ gval, float* __restrict__ out) {
    int gid = blockIdx.x * 256 + threadIdx.x;   // B*K*64 threads
    int s = gid >> 6, cq = (gid & 63) * 4;
    int b = s >> 9, i = s & (K_ - 1);
    int e = sel_e[b * K_ + i], t = sel_t[b * K_ + i];
    float g = gval[b * K_ + i];
#pragma unroll
    for (int q = 0; q < 4; ++q) {
        int c = cq + q;
        atomicAdd(out + (size_t)b * CT_ + (size_t)c * T_ + t,
                  scalec[c] * dw[(size_t)c * E_ + e] * g);
    }
}

extern "C" void kernel_launch(void* const* d_in, const int* in_sizes, int n_in,
                              void* d_out, int out_size, void* d_ws, size_t ws_size,
                              hipStream_t stream) {
    const float* x = (const float*)d_in[0];
    const float* up_w = (const float*)d_in[1];
    const float* up_b = (const float*)d_in[2];
    const float* mask_w = (const float*)d_in[3];
    const float* mask_b = (const float*)d_in[4];
    const float* sum_w = (const float*)d_in[5];
    const float* sum_b = (const float*)d_in[6];
    const float* down_w = (const float*)d_in[7];
    const float* down_b = (const float*)d_in[8];
    const float* bn_w = (const float*)d_in[9];
    const float* bn_b = (const float*)d_in[10];
    float* out = (float*)d_out;

    // workspace layout (floats); total ~5.6 MB
    float* ws = (float*)d_ws;
    size_t o = 0;
    float* rn = ws + o;   o += (size_t)B_ * T_;
    float* xs = ws + o;   o += (size_t)B_ * C_ * SCOLS_;
    float* msub = ws + o; o += (size_t)B_ * SUBN_;
    float* tau0 = ws + o; o += B_;
    float* Z = ws + o;    o += B_;
    int* cnt = (int*)(ws + o);   o += B_;
    float* cval = ws + o; o += (size_t)B_ * CAP_;
    int* cidx = (int*)(ws + o);  o += (size_t)B_ * CAP_;
    int* sel_e = (int*)(ws + o); o += (size_t)B_ * K_;
    int* sel_t = (int*)(ws + o); o += (size_t)B_ * K_;
    float* sel_sp = ws + o; o += (size_t)B_ * K_;
    float* gval = ws + o;   o += (size_t)B_ * K_;
    float* base = ws + o;   o += (size_t)B_ * C_;
    float* S1 = ws + o;     o += (size_t)B_ * C_;
    float* Qv = ws + o;     o += (size_t)B_ * C_;
    float* scalec = ws + o; o += C_;
    float* obase = ws + o;  o += (size_t)B_ * C_;

    k_rn<<<(B_ * T_) / 256, 256, 0, stream>>>(x, rn, Z, cnt);
    k_gather<<<(B_ * C_ * SCOLS_) / 256, 256, 0, stream>>>(x, rn, xs);
    k_msub2<<<dim3(SCOLS_ / 64, E_ / 64, B_), 256, 0, stream>>>(xs, mask_w, mask_b, msub);
    k_tau<<<B_, 256, 0, stream>>>(msub, tau0);
    k_gemm<<<dim3(T_ / 64, E_ / 64, B_), 256, 0, stream>>>(
        x, mask_w, mask_b, rn, tau0, Z, cnt, cval, cidx);
    k_select<<<B_, 256, 0, stream>>>(cval, cidx, cnt, Z, sel_e, sel_t, sel_sp);
    k_upg<<<(B_ * K_ * 64) / 256, 256, 0, stream>>>(x, up_w, up_b, sel_e, sel_t,
                                                    sel_sp, gval);
    k_bsq<<<(B_ * C_) / 4, 256, 0, stream>>>(sum_w, sum_b, down_b, down_w,
                                             sel_e, gval, base, S1, Qv);
    k_bnstats<<<1, C_, 0, stream>>>(base, S1, Qv, bn_w, bn_b, scalec, obase);
    k_fill<<<(B_ * CT_ / 4) / 256, 256, 0, stream>>>(obase, out);
    k_spikes<<<(B_ * K_ * 64) / 256, 256, 0, stream>>>(down_w, scalec, sel_e, sel_t,
                                                       gval, out);
}